// Round 3
// baseline (504.260 us; speedup 1.0000x reference)
//
#include <hip/hip_runtime.h>
#include <stdint.h>

constexpr int Bn = 8, Nn = 4096, Dn = 128, Cn = 256, Kn = 16;

// ---------------- Kernel A: exact KNN, fp32, BLAS-style rounding ----------------
// pd = ((-xx_n) + 2*inner) - xx_m, with
//   xx    = ((x*x) + (y*y)) + (z*z)          (rounded products, rounded adds; numpy temp+sum)
//   inner = fma(z,z', fma(y,y', x*x'))       (BLAS/Eigen k-ascending FMA chain)
// Top-16 under total order (value desc, index asc) == stable lax.top_k.
// One wave per row; 64 candidates/lane in registers; 16 rounds of wave argmax.
__global__ __launch_bounds__(256) void knn_kernel(const float* __restrict__ xyz, int* __restrict__ idxout)
{
    const int wave = threadIdx.x >> 6;
    const int lane = threadIdx.x & 63;
    const int row  = blockIdx.x * 4 + wave;
    const int b = row >> 12;               // N = 4096
    const int n = row & (Nn - 1);
    const float* xb = xyz + (size_t)b * Nn * 3;
    const float qx = xb[n * 3 + 0], qy = xb[n * 3 + 1], qz = xb[n * 3 + 2];
    const float xxq = __fadd_rn(__fadd_rn(__fmul_rn(qx, qx), __fmul_rn(qy, qy)), __fmul_rn(qz, qz));

    float v[64];
#pragma unroll
    for (int i = 0; i < 64; ++i) {
        const int m = (i << 6) + lane;
        const float px = xb[m * 3 + 0], py = xb[m * 3 + 1], pz = xb[m * 3 + 2];
        const float xxm = __fadd_rn(__fadd_rn(__fmul_rn(px, px), __fmul_rn(py, py)), __fmul_rn(pz, pz));
        const float inner = __builtin_fmaf(qz, pz, __builtin_fmaf(qy, py, __fmul_rn(qx, px)));
        v[i] = __fsub_rn(__fadd_rn(-xxq, __fmul_rn(2.0f, inner)), xxm);
    }

    unsigned long long used = 0ull;
    int sel = 0;
    for (int it = 0; it < Kn; ++it) {
        float bv = -3.0e38f;
        int bm = 0x7FFFFFFF;
#pragma unroll
        for (int i = 0; i < 64; ++i) {
            const bool freeslot = (used & (1ull << i)) == 0ull;
            if (freeslot && v[i] > bv) { bv = v[i]; bm = (i << 6) + lane; } // ascending m: tie -> lowest m
        }
#pragma unroll
        for (int off = 32; off; off >>= 1) {
            const float ov = __shfl_xor(bv, off);
            const int   om = __shfl_xor(bm, off);
            if (ov > bv || (ov == bv && om < bm)) { bv = ov; bm = om; }   // tie -> lowest index
        }
        if ((bm & 63) == lane) used |= (1ull << (bm >> 6));
        if (lane == it) sel = bm;
    }
    if (lane < Kn) idxout[row * Kn + lane] = sel;
}

// ---------------- Kernel B0: M = Wq^T @ Wk, v = bq @ Wk, u = Wq^T @ bk, w = bq . bk ----------------
__global__ __launch_bounds__(128) void prep_kernel(const float* __restrict__ Wq, const float* __restrict__ bq,
                                                   const float* __restrict__ Wk, const float* __restrict__ bk,
                                                   float* __restrict__ M, float* __restrict__ u,
                                                   float* __restrict__ v, float* __restrict__ w)
{
    const int dp = blockIdx.x;   // d'
    const int d  = threadIdx.x;  // d
    float acc = 0.f;
    for (int e = 0; e < Dn; ++e) acc = fmaf(Wq[e * Dn + dp], Wk[e * Dn + d], acc);
    M[dp * Dn + d] = acc;
    if (d == 0) {
        float a = 0.f;
        for (int e = 0; e < Dn; ++e) a = fmaf(Wq[e * Dn + dp], bk[e], a);
        u[dp] = a;
    }
    if (dp == 0) {
        float a = 0.f;
        for (int e = 0; e < Dn; ++e) a = fmaf(bq[e], Wk[e * Dn + d], a);
        v[d] = a;
        if (d == 0) {
            float s = 0.f;
            for (int e = 0; e < Dn; ++e) s = fmaf(bq[e], bk[e], s);
            *w = s;
        }
    }
}

// ---------------- Kernel B: t = concat @ M + v  ([32768x128] @ [128x128]) ----------------
__global__ __launch_bounds__(256) void tmat_kernel(const float* __restrict__ concat, const float* __restrict__ M,
                                                   const float* __restrict__ vvec, float* __restrict__ tout)
{
    __shared__ float As[64][33];
    __shared__ float Ms[32][128];
    const int tid = threadIdx.x;
    const int row0 = blockIdx.x * 64;
    const int tx = tid & 15;   // col group: cols tx*8 .. tx*8+7
    const int ty = tid >> 4;   // row group: rows ty*4 .. ty*4+3
    float acc[4][8];
#pragma unroll
    for (int r = 0; r < 4; ++r)
#pragma unroll
        for (int j = 0; j < 8; ++j) acc[r][j] = 0.f;

    for (int kc = 0; kc < 4; ++kc) {
        const int k0 = kc * 32;
        __syncthreads();
#pragma unroll
        for (int p = 0; p < 8; ++p) {
            const int e = p * 256 + tid;
            const int r = e >> 5, kk = e & 31;
            As[r][kk] = concat[(size_t)(row0 + r) * Dn + k0 + kk];
        }
#pragma unroll
        for (int p = 0; p < 16; ++p) {
            const int e = p * 256 + tid;
            const int kk = e >> 7, dd = e & 127;
            Ms[kk][dd] = M[(k0 + kk) * Dn + dd];
        }
        __syncthreads();
#pragma unroll
        for (int k = 0; k < 32; ++k) {
            const float4 mA = *(const float4*)(&Ms[k][tx * 8]);
            const float4 mB = *(const float4*)(&Ms[k][tx * 8 + 4]);
            const float mj[8] = {mA.x, mA.y, mA.z, mA.w, mB.x, mB.y, mB.z, mB.w};
#pragma unroll
            for (int r = 0; r < 4; ++r) {
                const float av = As[ty * 4 + r][k];
#pragma unroll
                for (int j = 0; j < 8; ++j) acc[r][j] = fmaf(av, mj[j], acc[r][j]);
            }
        }
    }
    float vv[8];
#pragma unroll
    for (int j = 0; j < 8; ++j) vv[j] = vvec[tx * 8 + j];
#pragma unroll
    for (int r = 0; r < 4; ++r)
#pragma unroll
        for (int j = 0; j < 8; ++j)
            tout[(size_t)(row0 + ty * 4 + r) * Dn + tx * 8 + j] = acc[r][j] + vv[j];
}

// ---------------- Kernel C: transpose fp4_features [B,C,N] -> featT [B,N,C] ----------------
__global__ __launch_bounds__(256) void transpose_kernel(const float* __restrict__ feat, float* __restrict__ featT)
{
    __shared__ float tile[32][33];
    const int n0 = blockIdx.x * 32;
    const int c0 = blockIdx.y * 32;
    const int b  = blockIdx.z;
    const int ln = threadIdx.x & 31, lg = threadIdx.x >> 5;  // 8 row-groups
    const float* fb = feat + (size_t)b * Cn * Nn;
#pragma unroll
    for (int p = 0; p < 4; ++p) {
        const int c = lg + p * 8;
        tile[c][ln] = fb[(size_t)(c0 + c) * Nn + n0 + ln];
    }
    __syncthreads();
    float* ob = featT + (size_t)b * Nn * Cn;
#pragma unroll
    for (int p = 0; p < 4; ++p) {
        const int nn = lg + p * 8;
        ob[(size_t)(n0 + nn) * Cn + c0 + ln] = tile[ln][nn];
    }
}

// ---------------- Kernel D: fused scores + softmax + neighbor-feature aggregation ----------------
__global__ __launch_bounds__(256) void fused_kernel(const float* __restrict__ concat, const float* __restrict__ tmat,
                                                    const float* __restrict__ featT, const int* __restrict__ knn,
                                                    const float* __restrict__ u, const float* __restrict__ wscal,
                                                    float* __restrict__ out)
{
    __shared__ float outs[16][256];
    const int wave = threadIdx.x >> 6;
    const int lane = threadIdx.x & 63;
    const int rbase = blockIdx.x * 16;
    const float u0 = u[lane], u1 = u[lane + 64];
    const float w = *wscal;
    const float scale = 0.08838834764831845f;  // 1/sqrt(128)

    for (int pt = 0; pt < 4; ++pt) {
        const int row = rbase + wave * 4 + pt;
        const int b = row >> 12;
        const float* cb = concat + (size_t)row * Dn;
        const float t0 = tmat[(size_t)row * Dn + lane];
        const float t1 = tmat[(size_t)row * Dn + 64 + lane];
        const float cn0 = cb[lane], cn1 = cb[64 + lane];

        float pz = t0 * cn0 + t1 * cn1;   // -> z = t . c_n
        float ps = cn0 * u0 + cn1 * u1;   // -> s0 = c_n . u + w
#pragma unroll
        for (int off = 32; off; off >>= 1) {
            pz += __shfl_xor(pz, off);
            ps += __shfl_xor(ps, off);
        }
        const float zz = pz;
        const float s0 = ps + w;

        int myidx = 0;
        if (lane < Kn) myidx = knn[row * Kn + lane];

        float p[16];
#pragma unroll
        for (int j = 0; j < 16; ++j) {
            const int ij = __shfl(myidx, j);
            const float* cj = concat + ((size_t)b * Nn + ij) * Dn;
            p[j] = t0 * cj[lane] + t1 * cj[64 + lane];
        }
#pragma unroll
        for (int off = 32; off; off >>= 1) {
#pragma unroll
            for (int j = 0; j < 16; ++j) p[j] += __shfl_xor(p[j], off);
        }

        float mx = -3.0e38f;
#pragma unroll
        for (int j = 0; j < 16; ++j) {
            p[j] = (p[j] - zz + s0) * scale;
            mx = fmaxf(mx, p[j]);
        }
        float sum = 0.f;
#pragma unroll
        for (int j = 0; j < 16; ++j) { p[j] = __expf(p[j] - mx); sum += p[j]; }
        const float inv = 1.0f / sum;

        float4 acc = make_float4(0.f, 0.f, 0.f, 0.f);
#pragma unroll
        for (int j = 0; j < 16; ++j) {
            const int ij = __shfl(myidx, j);
            const float4 f = *(const float4*)(&featT[((size_t)b * Nn + ij) * Cn + lane * 4]);
            const float a = p[j] * inv;
            acc.x = fmaf(a, f.x, acc.x);
            acc.y = fmaf(a, f.y, acc.y);
            acc.z = fmaf(a, f.z, acc.z);
            acc.w = fmaf(a, f.w, acc.w);
        }
        *(float4*)(&outs[wave * 4 + pt][lane * 4]) = acc;
    }
    __syncthreads();

    const int b = rbase >> 12;
    const int n0 = rbase & (Nn - 1);
#pragma unroll
    for (int p2 = 0; p2 < 16; ++p2) {
        const int c  = (threadIdx.x >> 4) + p2 * 16;
        const int nn = threadIdx.x & 15;
        out[((size_t)b * Cn + c) * Nn + n0 + nn] = outs[nn][c];
    }
}

extern "C" void kernel_launch(void* const* d_in, const int* in_sizes, int n_in,
                              void* d_out, int out_size, void* d_ws, size_t ws_size,
                              hipStream_t stream) {
    const float* xyz    = (const float*)d_in[0];   // [B,N,3]
    const float* feat   = (const float*)d_in[1];   // [B,C,N]
    const float* concat = (const float*)d_in[2];   // [B,N,D]
    const float* Wq     = (const float*)d_in[3];
    const float* bq     = (const float*)d_in[4];
    const float* Wk     = (const float*)d_in[5];
    const float* bk     = (const float*)d_in[6];
    float* out = (float*)d_out;
    float* ws  = (float*)d_ws;

    // workspace layout (float units), all offsets 256B-aligned
    float* M     = ws;                 // 16384
    float* u     = ws + 16384;         // 128
    float* v     = ws + 16512;         // 128
    float* w     = ws + 16640;         // 1
    int*   idx   = (int*)(ws + 16704); // 32768*16 ints
    float* t     = ws + 540992;        // 32768*128
    float* featT = ws + 4735296;       // 8*4096*256
    // total: 13,123,904 floats = 52.5 MB

    hipLaunchKernelGGL(prep_kernel,      dim3(128),        dim3(128), 0, stream, Wq, bq, Wk, bk, M, u, v, w);
    hipLaunchKernelGGL(knn_kernel,       dim3(8192),       dim3(256), 0, stream, xyz, idx);
    hipLaunchKernelGGL(tmat_kernel,      dim3(512),        dim3(256), 0, stream, concat, M, v, t);
    hipLaunchKernelGGL(transpose_kernel, dim3(128, 8, 8),  dim3(256), 0, stream, feat, featT);
    hipLaunchKernelGGL(fused_kernel,     dim3(2048),       dim3(256), 0, stream, concat, t, featT, idx, u, w, out);
}

// Round 4
// 305.706 us; speedup vs baseline: 1.6495x; 1.6495x over previous
//
#include <hip/hip_runtime.h>
#include <stdint.h>

constexpr int Bn = 8, Nn = 4096, Dn = 128, Cn = 256, Kn = 16;

// ---------------- Kernel A0: pack xyz -> float4 (x,y,z,xx), xx = ((x*x)+(y*y))+(z*z) exact ----------------
__global__ __launch_bounds__(256) void pack_kernel(const float* __restrict__ xyz, float4* __restrict__ xyzw)
{
    const int p = blockIdx.x * 256 + threadIdx.x;   // 32768 points
    const float x = xyz[p * 3 + 0], y = xyz[p * 3 + 1], z = xyz[p * 3 + 2];
    const float xx = __fadd_rn(__fadd_rn(__fmul_rn(x, x), __fmul_rn(y, y)), __fmul_rn(z, z));
    xyzw[p] = make_float4(x, y, z, xx);
}

// ---------------- Kernel A: exact KNN, fp32, threshold-filtered top-16 ----------------
// pd = ((-xx_n) + 2*inner) - xx_m  (bit-identical to the passing round-3 formula;
// inner = fma(z,z', fma(y,y', x*x')) BLAS-style chain).
// Selection: L = 16th-largest per-lane max (valid lower bound for global 16th);
// survivors (v >= L) compacted to LDS in index order; 16 shuffle-argmax rounds.
// Safety: S>=16 guarantees the filtered set contains the exact top-16; otherwise
// (or S>256) fall back to the exhaustive rescan (always correct).
__global__ __launch_bounds__(256) void knn_kernel(const float4* __restrict__ xyzw, int* __restrict__ idxout)
{
    __shared__ float lv[4][256];
    __shared__ int   li[4][256];
    const int wave = threadIdx.x >> 6;
    const int lane = threadIdx.x & 63;
    const int row  = blockIdx.x * 4 + wave;
    const int n = row & (Nn - 1);
    const float4* xb = xyzw + (size_t)(row >> 12) * Nn;
    const float4 Q = xb[n];
    const float xxq = Q.w;

    float v[64];
    float lm = -3.0e38f;
#pragma unroll
    for (int i = 0; i < 64; ++i) {
        const float4 P = xb[(i << 6) + lane];
        const float inner = __builtin_fmaf(Q.z, P.z, __builtin_fmaf(Q.y, P.y, __fmul_rn(Q.x, P.x)));
        v[i] = __fsub_rn(__fadd_rn(-xxq, __fmul_rn(2.0f, inner)), P.w);
        lm = fmaxf(lm, v[i]);
    }

    // descending bitonic sort of the 64 lane maxima; L = value at rank 15
    float s = lm;
#pragma unroll
    for (int k = 2; k <= 64; k <<= 1) {
#pragma unroll
        for (int j = k >> 1; j > 0; j >>= 1) {
            const float o = __shfl_xor(s, j);
            const bool takeMax = ((lane & j) == 0) ^ ((lane & k) != 0);
            s = takeMax ? fmaxf(s, o) : fminf(s, o);
        }
    }
    const float L = __shfl(s, 15);

    // compact survivors (v >= L) into per-wave LDS list, global-index ascending
    const unsigned long long lt = (1ull << lane) - 1ull;
    int base = 0;
#pragma unroll
    for (int i = 0; i < 64; ++i) {
        const bool pred = v[i] >= L;
        const unsigned long long mk = __ballot(pred);
        if (mk != 0ull) {
            if (pred) {
                const int pos = base + (int)__popcll(mk & lt);
                if (pos < 256) { lv[wave][pos] = v[i]; li[wave][pos] = (i << 6) + lane; }
            }
            base += (int)__popcll(mk);
        }
    }
    const int S = base;

    int sel = 0;
    if (S >= 16 && S <= 64) {
        // one survivor per lane
        float bv0 = -3.0e38f; int bm0 = 0x7FFFFFFF;
        if (lane < S) { bv0 = lv[wave][lane]; bm0 = li[wave][lane]; }
        for (int it = 0; it < Kn; ++it) {
            float bv = bv0; int bm = bm0;
#pragma unroll
            for (int off = 32; off; off >>= 1) {
                const float ov = __shfl_xor(bv, off);
                const int   om = __shfl_xor(bm, off);
                if (ov > bv || (ov == bv && om < bm)) { bv = ov; bm = om; }
            }
            if (bm == bm0) bv0 = -3.0e38f;   // global indices unique -> removes exactly the winner
            if (lane == it) sel = bm;
        }
    } else if (S > 64 && S <= 256) {
        // up to four survivors per lane
        float ev[4]; int em[4];
#pragma unroll
        for (int e = 0; e < 4; ++e) {
            const int pos = lane + (e << 6);
            const bool ok = pos < S;
            ev[e] = ok ? lv[wave][pos] : -3.0e38f;
            em[e] = ok ? li[wave][pos] : 0x7FFFFFFF;
        }
        for (int it = 0; it < Kn; ++it) {
            float bv = ev[0]; int bm = em[0];
#pragma unroll
            for (int e = 1; e < 4; ++e)
                if (ev[e] > bv || (ev[e] == bv && em[e] < bm)) { bv = ev[e]; bm = em[e]; }
#pragma unroll
            for (int off = 32; off; off >>= 1) {
                const float ov = __shfl_xor(bv, off);
                const int   om = __shfl_xor(bm, off);
                if (ov > bv || (ov == bv && om < bm)) { bv = ov; bm = om; }
            }
#pragma unroll
            for (int e = 0; e < 4; ++e) if (em[e] == bm) ev[e] = -3.0e38f;
            if (lane == it) sel = bm;
        }
    } else {
        // fallback: exhaustive 16-round rescan (the round-3 passing path)
        unsigned long long used = 0ull;
        for (int it = 0; it < Kn; ++it) {
            float bv = -3.0e38f; int bm = 0x7FFFFFFF;
#pragma unroll
            for (int i = 0; i < 64; ++i) {
                const bool freeslot = (used & (1ull << i)) == 0ull;
                if (freeslot && v[i] > bv) { bv = v[i]; bm = (i << 6) + lane; }
            }
#pragma unroll
            for (int off = 32; off; off >>= 1) {
                const float ov = __shfl_xor(bv, off);
                const int   om = __shfl_xor(bm, off);
                if (ov > bv || (ov == bv && om < bm)) { bv = ov; bm = om; }
            }
            if ((bm & 63) == lane) used |= (1ull << (bm >> 6));
            if (lane == it) sel = bm;
        }
    }
    if (lane < Kn) idxout[row * Kn + lane] = sel;
}

// ---------------- Kernel B0: M = Wq^T @ Wk, v = bq @ Wk, u = Wq^T @ bk, w = bq . bk ----------------
__global__ __launch_bounds__(128) void prep_kernel(const float* __restrict__ Wq, const float* __restrict__ bq,
                                                   const float* __restrict__ Wk, const float* __restrict__ bk,
                                                   float* __restrict__ M, float* __restrict__ u,
                                                   float* __restrict__ v, float* __restrict__ w)
{
    const int dp = blockIdx.x;   // d'
    const int d  = threadIdx.x;  // d
    float acc = 0.f;
    for (int e = 0; e < Dn; ++e) acc = fmaf(Wq[e * Dn + dp], Wk[e * Dn + d], acc);
    M[dp * Dn + d] = acc;
    if (d == 0) {
        float a = 0.f;
        for (int e = 0; e < Dn; ++e) a = fmaf(Wq[e * Dn + dp], bk[e], a);
        u[dp] = a;
    }
    if (dp == 0) {
        float a = 0.f;
        for (int e = 0; e < Dn; ++e) a = fmaf(bq[e], Wk[e * Dn + d], a);
        v[d] = a;
        if (d == 0) {
            float s = 0.f;
            for (int e = 0; e < Dn; ++e) s = fmaf(bq[e], bk[e], s);
            *w = s;
        }
    }
}

// ---------------- Kernel B: t = concat @ M + v  ([32768x128] @ [128x128]) ----------------
__global__ __launch_bounds__(256) void tmat_kernel(const float* __restrict__ concat, const float* __restrict__ M,
                                                   const float* __restrict__ vvec, float* __restrict__ tout)
{
    __shared__ float As[64][33];
    __shared__ float Ms[32][128];
    const int tid = threadIdx.x;
    const int row0 = blockIdx.x * 64;
    const int tx = tid & 15;   // col group: cols tx*8 .. tx*8+7
    const int ty = tid >> 4;   // row group: rows ty*4 .. ty*4+3
    float acc[4][8];
#pragma unroll
    for (int r = 0; r < 4; ++r)
#pragma unroll
        for (int j = 0; j < 8; ++j) acc[r][j] = 0.f;

    for (int kc = 0; kc < 4; ++kc) {
        const int k0 = kc * 32;
        __syncthreads();
#pragma unroll
        for (int p = 0; p < 8; ++p) {
            const int e = p * 256 + tid;
            const int r = e >> 5, kk = e & 31;
            As[r][kk] = concat[(size_t)(row0 + r) * Dn + k0 + kk];
        }
#pragma unroll
        for (int p = 0; p < 16; ++p) {
            const int e = p * 256 + tid;
            const int kk = e >> 7, dd = e & 127;
            Ms[kk][dd] = M[(k0 + kk) * Dn + dd];
        }
        __syncthreads();
#pragma unroll
        for (int k = 0; k < 32; ++k) {
            const float4 mA = *(const float4*)(&Ms[k][tx * 8]);
            const float4 mB = *(const float4*)(&Ms[k][tx * 8 + 4]);
            const float mj[8] = {mA.x, mA.y, mA.z, mA.w, mB.x, mB.y, mB.z, mB.w};
#pragma unroll
            for (int r = 0; r < 4; ++r) {
                const float av = As[ty * 4 + r][k];
#pragma unroll
                for (int j = 0; j < 8; ++j) acc[r][j] = fmaf(av, mj[j], acc[r][j]);
            }
        }
    }
    float vv[8];
#pragma unroll
    for (int j = 0; j < 8; ++j) vv[j] = vvec[tx * 8 + j];
#pragma unroll
    for (int r = 0; r < 4; ++r)
#pragma unroll
        for (int j = 0; j < 8; ++j)
            tout[(size_t)(row0 + ty * 4 + r) * Dn + tx * 8 + j] = acc[r][j] + vv[j];
}

// ---------------- Kernel C: transpose fp4_features [B,C,N] -> featT [B,N,C] ----------------
__global__ __launch_bounds__(256) void transpose_kernel(const float* __restrict__ feat, float* __restrict__ featT)
{
    __shared__ float tile[32][33];
    const int n0 = blockIdx.x * 32;
    const int c0 = blockIdx.y * 32;
    const int b  = blockIdx.z;
    const int ln = threadIdx.x & 31, lg = threadIdx.x >> 5;  // 8 row-groups
    const float* fb = feat + (size_t)b * Cn * Nn;
#pragma unroll
    for (int p = 0; p < 4; ++p) {
        const int c = lg + p * 8;
        tile[c][ln] = fb[(size_t)(c0 + c) * Nn + n0 + ln];
    }
    __syncthreads();
    float* ob = featT + (size_t)b * Nn * Cn;
#pragma unroll
    for (int p = 0; p < 4; ++p) {
        const int nn = lg + p * 8;
        ob[(size_t)(n0 + nn) * Cn + c0 + ln] = tile[ln][nn];
    }
}

// ---------------- Kernel D: fused scores + softmax + neighbor-feature aggregation ----------------
__global__ __launch_bounds__(256) void fused_kernel(const float* __restrict__ concat, const float* __restrict__ tmat,
                                                    const float* __restrict__ featT, const int* __restrict__ knn,
                                                    const float* __restrict__ u, const float* __restrict__ wscal,
                                                    float* __restrict__ out)
{
    __shared__ float outs[16][256];
    const int wave = threadIdx.x >> 6;
    const int lane = threadIdx.x & 63;
    const int rbase = blockIdx.x * 16;
    const float u0 = u[lane], u1 = u[lane + 64];
    const float w = *wscal;
    const float scale = 0.08838834764831845f;  // 1/sqrt(128)

    for (int pt = 0; pt < 4; ++pt) {
        const int row = rbase + wave * 4 + pt;
        const int b = row >> 12;
        const float* cb = concat + (size_t)row * Dn;
        const float t0 = tmat[(size_t)row * Dn + lane];
        const float t1 = tmat[(size_t)row * Dn + 64 + lane];
        const float cn0 = cb[lane], cn1 = cb[64 + lane];

        float pz = t0 * cn0 + t1 * cn1;   // -> z = t . c_n
        float ps = cn0 * u0 + cn1 * u1;   // -> s0 = c_n . u + w
#pragma unroll
        for (int off = 32; off; off >>= 1) {
            pz += __shfl_xor(pz, off);
            ps += __shfl_xor(ps, off);
        }
        const float zz = pz;
        const float s0 = ps + w;

        int myidx = 0;
        if (lane < Kn) myidx = knn[row * Kn + lane];

        float p[16];
#pragma unroll
        for (int j = 0; j < 16; ++j) {
            const int ij = __shfl(myidx, j);
            const float* cj = concat + ((size_t)b * Nn + ij) * Dn;
            p[j] = t0 * cj[lane] + t1 * cj[64 + lane];
        }
#pragma unroll
        for (int off = 32; off; off >>= 1) {
#pragma unroll
            for (int j = 0; j < 16; ++j) p[j] += __shfl_xor(p[j], off);
        }

        float mx = -3.0e38f;
#pragma unroll
        for (int j = 0; j < 16; ++j) {
            p[j] = (p[j] - zz + s0) * scale;
            mx = fmaxf(mx, p[j]);
        }
        float sum = 0.f;
#pragma unroll
        for (int j = 0; j < 16; ++j) { p[j] = __expf(p[j] - mx); sum += p[j]; }
        const float inv = 1.0f / sum;

        float4 acc = make_float4(0.f, 0.f, 0.f, 0.f);
#pragma unroll
        for (int j = 0; j < 16; ++j) {
            const int ij = __shfl(myidx, j);
            const float4 f = *(const float4*)(&featT[((size_t)b * Nn + ij) * Cn + lane * 4]);
            const float a = p[j] * inv;
            acc.x = fmaf(a, f.x, acc.x);
            acc.y = fmaf(a, f.y, acc.y);
            acc.z = fmaf(a, f.z, acc.z);
            acc.w = fmaf(a, f.w, acc.w);
        }
        *(float4*)(&outs[wave * 4 + pt][lane * 4]) = acc;
    }
    __syncthreads();

    const int b = rbase >> 12;
    const int n0 = rbase & (Nn - 1);
#pragma unroll
    for (int p2 = 0; p2 < 16; ++p2) {
        const int c  = (threadIdx.x >> 4) + p2 * 16;
        const int nn = threadIdx.x & 15;
        out[((size_t)b * Cn + c) * Nn + n0 + nn] = outs[nn][c];
    }
}

extern "C" void kernel_launch(void* const* d_in, const int* in_sizes, int n_in,
                              void* d_out, int out_size, void* d_ws, size_t ws_size,
                              hipStream_t stream) {
    const float* xyz    = (const float*)d_in[0];   // [B,N,3]
    const float* feat   = (const float*)d_in[1];   // [B,C,N]
    const float* concat = (const float*)d_in[2];   // [B,N,D]
    const float* Wq     = (const float*)d_in[3];
    const float* bq     = (const float*)d_in[4];
    const float* Wk     = (const float*)d_in[5];
    const float* bk     = (const float*)d_in[6];
    float* out = (float*)d_out;
    float* ws  = (float*)d_ws;

    // workspace layout (float units), offsets 16B-aligned
    float*  M     = ws;                 // 16384
    float*  u     = ws + 16384;         // 128
    float*  v     = ws + 16512;         // 128
    float*  w     = ws + 16640;         // 1
    int*    idx   = (int*)(ws + 16704); // 32768*16 ints
    float*  t     = ws + 540992;        // 32768*128
    float*  featT = ws + 4735296;       // 8*4096*256
    float4* xyzw  = (float4*)(ws + 13123904); // 32768 float4 = 131072 floats
    // total: 13,254,976 floats = 53.0 MB

    hipLaunchKernelGGL(pack_kernel,      dim3(128),        dim3(256), 0, stream, xyz, xyzw);
    hipLaunchKernelGGL(prep_kernel,      dim3(128),        dim3(128), 0, stream, Wq, bq, Wk, bk, M, u, v, w);
    hipLaunchKernelGGL(knn_kernel,       dim3(8192),       dim3(256), 0, stream, xyzw, idx);
    hipLaunchKernelGGL(tmat_kernel,      dim3(512),        dim3(256), 0, stream, concat, M, v, t);
    hipLaunchKernelGGL(transpose_kernel, dim3(128, 8, 8),  dim3(256), 0, stream, feat, featT);
    hipLaunchKernelGGL(fused_kernel,     dim3(2048),       dim3(256), 0, stream, concat, t, featT, idx, u, w, out);
}

// Round 5
// 268.147 us; speedup vs baseline: 1.8805x; 1.1401x over previous
//
#include <hip/hip_runtime.h>
#include <stdint.h>

constexpr int Bn = 8, Nn = 4096, Dn = 128, Cn = 256, Kn = 16;

// ---------------- Kernel A0: pack xyz -> float4 (x,y,z,xx), xx = ((x*x)+(y*y))+(z*z) exact ----------------
__global__ __launch_bounds__(256) void pack_kernel(const float* __restrict__ xyz, float4* __restrict__ xyzw)
{
    const int p = blockIdx.x * 256 + threadIdx.x;   // 32768 points
    const float x = xyz[p * 3 + 0], y = xyz[p * 3 + 1], z = xyz[p * 3 + 2];
    const float xx = __fadd_rn(__fadd_rn(__fmul_rn(x, x), __fmul_rn(y, y)), __fmul_rn(z, z));
    xyzw[p] = make_float4(x, y, z, xx);
}

// ---------------- Kernel A: exact KNN, fp32, threshold-filter + bitonic pair-sort ----------------
// pd = ((-xx_n) + 2*inner) - xx_m   (bit-identical to the round-3/4 passing formula;
// inner = fma(z,z', fma(y,y', x*x')) BLAS-style chain).
// L = 16th-largest per-lane max  =>  survivors {v >= L} always contain the top-16 (S >= 16
// by construction). Compact survivors one-per-lane into LDS; 21-step bitonic sort of
// (value desc, index asc) pairs leaves the k-th neighbor in lane k. S > 64 (vanishing
// probability) falls back to the exhaustive 16-round rescan (always correct).
__global__ __launch_bounds__(256) void knn_kernel(const float4* __restrict__ xyzw, int* __restrict__ idxout)
{
    __shared__ float lv[4][64];
    __shared__ int   li[4][64];
    const int wave = threadIdx.x >> 6;
    const int lane = threadIdx.x & 63;
    const int row  = blockIdx.x * 4 + wave;
    const int n = row & (Nn - 1);
    const float4* xb = xyzw + (size_t)(row >> 12) * Nn;
    const float4 Q = xb[n];
    const float xxq = Q.w;

    float v[64];
    float lm = -3.0e38f;
#pragma unroll
    for (int i = 0; i < 64; ++i) {
        const float4 P = xb[(i << 6) + lane];
        const float inner = __builtin_fmaf(Q.z, P.z, __builtin_fmaf(Q.y, P.y, __fmul_rn(Q.x, P.x)));
        v[i] = __fsub_rn(__fadd_rn(-xxq, __fmul_rn(2.0f, inner)), P.w);
        lm = fmaxf(lm, v[i]);
    }

    // descending bitonic sort of the 64 lane maxima; L = value at rank 15
    float s = lm;
#pragma unroll
    for (int k = 2; k <= 64; k <<= 1) {
#pragma unroll
        for (int j = k >> 1; j > 0; j >>= 1) {
            const float o = __shfl_xor(s, j);
            const bool takeMax = ((lane & j) == 0) ^ ((lane & k) != 0);
            s = takeMax ? fmaxf(s, o) : fminf(s, o);
        }
    }
    const float L = __shfl(s, 15);

    // compact survivors (v >= L) into per-wave LDS list (index-ascending order)
    const unsigned long long lt = (1ull << lane) - 1ull;
    int base = 0;
#pragma unroll
    for (int i = 0; i < 64; ++i) {
        const bool pred = v[i] >= L;
        const unsigned long long mk = __ballot(pred);
        if (mk != 0ull) {
            if (pred) {
                const int pos = base + (int)__popcll(mk & lt);
                if (pos < 64) { lv[wave][pos] = v[i]; li[wave][pos] = (i << 6) + lane; }
            }
            base += (int)__popcll(mk);
        }
    }
    const int S = base;

    int sel = 0;
    if (S <= 64) {
        // one survivor per lane; full bitonic sort of (value desc, index asc) pairs
        float pv = -3.0e38f; int pi = 0x7FFFFFFF;
        if (lane < S) { pv = lv[wave][lane]; pi = li[wave][lane]; }
#pragma unroll
        for (int k = 2; k <= 64; k <<= 1) {
#pragma unroll
            for (int j = k >> 1; j > 0; j >>= 1) {
                const float ov = __shfl_xor(pv, j);
                const int   oi = __shfl_xor(pi, j);
                const bool takeHi = ((lane & j) == 0) ^ ((lane & k) != 0);
                const bool ogt = (ov > pv) || (ov == pv && oi < pi);   // strict total order (indices unique)
                const bool take_o = takeHi ? ogt : !ogt;
                pv = take_o ? ov : pv;
                pi = take_o ? oi : pi;
            }
        }
        sel = pi;   // lane k holds the k-th nearest neighbor
    } else {
        // fallback: exhaustive 16-round rescan (the round-3 passing path)
        unsigned long long used = 0ull;
        for (int it = 0; it < Kn; ++it) {
            float bv = -3.0e38f; int bm = 0x7FFFFFFF;
#pragma unroll
            for (int i = 0; i < 64; ++i) {
                const bool freeslot = (used & (1ull << i)) == 0ull;
                if (freeslot && v[i] > bv) { bv = v[i]; bm = (i << 6) + lane; }
            }
#pragma unroll
            for (int off = 32; off; off >>= 1) {
                const float ov = __shfl_xor(bv, off);
                const int   om = __shfl_xor(bm, off);
                if (ov > bv || (ov == bv && om < bm)) { bv = ov; bm = om; }
            }
            if ((bm & 63) == lane) used |= (1ull << (bm >> 6));
            if (lane == it) sel = bm;
        }
    }
    if (lane < Kn) idxout[row * Kn + lane] = sel;
}

// ---------------- Kernel B0: M = Wq^T @ Wk, v = bq @ Wk, u = Wq^T @ bk, w = bq . bk ----------------
__global__ __launch_bounds__(128) void prep_kernel(const float* __restrict__ Wq, const float* __restrict__ bq,
                                                   const float* __restrict__ Wk, const float* __restrict__ bk,
                                                   float* __restrict__ M, float* __restrict__ u,
                                                   float* __restrict__ v, float* __restrict__ w)
{
    const int dp = blockIdx.x;   // d'
    const int d  = threadIdx.x;  // d
    float acc = 0.f;
    for (int e = 0; e < Dn; ++e) acc = fmaf(Wq[e * Dn + dp], Wk[e * Dn + d], acc);
    M[dp * Dn + d] = acc;
    if (d == 0) {
        float a = 0.f;
        for (int e = 0; e < Dn; ++e) a = fmaf(Wq[e * Dn + dp], bk[e], a);
        u[dp] = a;
    }
    if (dp == 0) {
        float a = 0.f;
        for (int e = 0; e < Dn; ++e) a = fmaf(bq[e], Wk[e * Dn + d], a);
        v[d] = a;
        if (d == 0) {
            float s = 0.f;
            for (int e = 0; e < Dn; ++e) s = fmaf(bq[e], bk[e], s);
            *w = s;
        }
    }
}

// ---------------- Kernel B: t = concat @ M + v  ([32768x128] @ [128x128]) ----------------
__global__ __launch_bounds__(256) void tmat_kernel(const float* __restrict__ concat, const float* __restrict__ M,
                                                   const float* __restrict__ vvec, float* __restrict__ tout)
{
    __shared__ float As[64][33];
    __shared__ float Ms[32][128];
    const int tid = threadIdx.x;
    const int row0 = blockIdx.x * 64;
    const int tx = tid & 15;   // col group: cols tx*8 .. tx*8+7
    const int ty = tid >> 4;   // row group: rows ty*4 .. ty*4+3
    float acc[4][8];
#pragma unroll
    for (int r = 0; r < 4; ++r)
#pragma unroll
        for (int j = 0; j < 8; ++j) acc[r][j] = 0.f;

    for (int kc = 0; kc < 4; ++kc) {
        const int k0 = kc * 32;
        __syncthreads();
#pragma unroll
        for (int p = 0; p < 8; ++p) {
            const int e = p * 256 + tid;
            const int r = e >> 5, kk = e & 31;
            As[r][kk] = concat[(size_t)(row0 + r) * Dn + k0 + kk];
        }
#pragma unroll
        for (int p = 0; p < 16; ++p) {
            const int e = p * 256 + tid;
            const int kk = e >> 7, dd = e & 127;
            Ms[kk][dd] = M[(k0 + kk) * Dn + dd];
        }
        __syncthreads();
#pragma unroll
        for (int k = 0; k < 32; ++k) {
            const float4 mA = *(const float4*)(&Ms[k][tx * 8]);
            const float4 mB = *(const float4*)(&Ms[k][tx * 8 + 4]);
            const float mj[8] = {mA.x, mA.y, mA.z, mA.w, mB.x, mB.y, mB.z, mB.w};
#pragma unroll
            for (int r = 0; r < 4; ++r) {
                const float av = As[ty * 4 + r][k];
#pragma unroll
                for (int j = 0; j < 8; ++j) acc[r][j] = fmaf(av, mj[j], acc[r][j]);
            }
        }
    }
    float vv[8];
#pragma unroll
    for (int j = 0; j < 8; ++j) vv[j] = vvec[tx * 8 + j];
#pragma unroll
    for (int r = 0; r < 4; ++r)
#pragma unroll
        for (int j = 0; j < 8; ++j)
            tout[(size_t)(row0 + ty * 4 + r) * Dn + tx * 8 + j] = acc[r][j] + vv[j];
}

// ---------------- Kernel C: transpose fp4_features [B,C,N] -> featT [B,N,C] ----------------
__global__ __launch_bounds__(256) void transpose_kernel(const float* __restrict__ feat, float* __restrict__ featT)
{
    __shared__ float tile[32][33];
    const int n0 = blockIdx.x * 32;
    const int c0 = blockIdx.y * 32;
    const int b  = blockIdx.z;
    const int ln = threadIdx.x & 31, lg = threadIdx.x >> 5;  // 8 row-groups
    const float* fb = feat + (size_t)b * Cn * Nn;
#pragma unroll
    for (int p = 0; p < 4; ++p) {
        const int c = lg + p * 8;
        tile[c][ln] = fb[(size_t)(c0 + c) * Nn + n0 + ln];
    }
    __syncthreads();
    float* ob = featT + (size_t)b * Nn * Cn;
#pragma unroll
    for (int p = 0; p < 4; ++p) {
        const int nn = lg + p * 8;
        ob[(size_t)(n0 + nn) * Cn + c0 + ln] = tile[ln][nn];
    }
}

// ---------------- Kernel D: fused scores + softmax + neighbor-feature aggregation ----------------
__global__ __launch_bounds__(256) void fused_kernel(const float* __restrict__ concat, const float* __restrict__ tmat,
                                                    const float* __restrict__ featT, const int* __restrict__ knn,
                                                    const float* __restrict__ u, const float* __restrict__ wscal,
                                                    float* __restrict__ out)
{
    __shared__ float outs[16][256];
    const int wave = threadIdx.x >> 6;
    const int lane = threadIdx.x & 63;
    const int rbase = blockIdx.x * 16;
    const float u0 = u[lane], u1 = u[lane + 64];
    const float w = *wscal;
    const float scale = 0.08838834764831845f;  // 1/sqrt(128)

    for (int pt = 0; pt < 4; ++pt) {
        const int row = rbase + wave * 4 + pt;
        const int b = row >> 12;
        const float* cb = concat + (size_t)row * Dn;
        const float t0 = tmat[(size_t)row * Dn + lane];
        const float t1 = tmat[(size_t)row * Dn + 64 + lane];
        const float cn0 = cb[lane], cn1 = cb[64 + lane];

        float pz = t0 * cn0 + t1 * cn1;   // -> z = t . c_n
        float ps = cn0 * u0 + cn1 * u1;   // -> s0 = c_n . u + w
#pragma unroll
        for (int off = 32; off; off >>= 1) {
            pz += __shfl_xor(pz, off);
            ps += __shfl_xor(ps, off);
        }
        const float zz = pz;
        const float s0 = ps + w;

        int myidx = 0;
        if (lane < Kn) myidx = knn[row * Kn + lane];

        float p[16];
#pragma unroll
        for (int j = 0; j < 16; ++j) {
            const int ij = __shfl(myidx, j);
            const float* cj = concat + ((size_t)b * Nn + ij) * Dn;
            p[j] = t0 * cj[lane] + t1 * cj[64 + lane];
        }
#pragma unroll
        for (int off = 32; off; off >>= 1) {
#pragma unroll
            for (int j = 0; j < 16; ++j) p[j] += __shfl_xor(p[j], off);
        }

        float mx = -3.0e38f;
#pragma unroll
        for (int j = 0; j < 16; ++j) {
            p[j] = (p[j] - zz + s0) * scale;
            mx = fmaxf(mx, p[j]);
        }
        float sum = 0.f;
#pragma unroll
        for (int j = 0; j < 16; ++j) { p[j] = __expf(p[j] - mx); sum += p[j]; }
        const float inv = 1.0f / sum;

        float4 acc = make_float4(0.f, 0.f, 0.f, 0.f);
#pragma unroll
        for (int j = 0; j < 16; ++j) {
            const int ij = __shfl(myidx, j);
            const float4 f = *(const float4*)(&featT[((size_t)b * Nn + ij) * Cn + lane * 4]);
            const float a = p[j] * inv;
            acc.x = fmaf(a, f.x, acc.x);
            acc.y = fmaf(a, f.y, acc.y);
            acc.z = fmaf(a, f.z, acc.z);
            acc.w = fmaf(a, f.w, acc.w);
        }
        *(float4*)(&outs[wave * 4 + pt][lane * 4]) = acc;
    }
    __syncthreads();

    const int b = rbase >> 12;
    const int n0 = rbase & (Nn - 1);
#pragma unroll
    for (int p2 = 0; p2 < 16; ++p2) {
        const int c  = (threadIdx.x >> 4) + p2 * 16;
        const int nn = threadIdx.x & 15;
        out[((size_t)b * Cn + c) * Nn + n0 + nn] = outs[nn][c];
    }
}

extern "C" void kernel_launch(void* const* d_in, const int* in_sizes, int n_in,
                              void* d_out, int out_size, void* d_ws, size_t ws_size,
                              hipStream_t stream) {
    const float* xyz    = (const float*)d_in[0];   // [B,N,3]
    const float* feat   = (const float*)d_in[1];   // [B,C,N]
    const float* concat = (const float*)d_in[2];   // [B,N,D]
    const float* Wq     = (const float*)d_in[3];
    const float* bq     = (const float*)d_in[4];
    const float* Wk     = (const float*)d_in[5];
    const float* bk     = (const float*)d_in[6];
    float* out = (float*)d_out;
    float* ws  = (float*)d_ws;

    // workspace layout (float units), offsets 16B-aligned
    float*  M     = ws;                 // 16384
    float*  u     = ws + 16384;         // 128
    float*  v     = ws + 16512;         // 128
    float*  w     = ws + 16640;         // 1
    int*    idx   = (int*)(ws + 16704); // 32768*16 ints
    float*  t     = ws + 540992;        // 32768*128
    float*  featT = ws + 4735296;       // 8*4096*256
    float4* xyzw  = (float4*)(ws + 13123904); // 32768 float4 = 131072 floats
    // total: 13,254,976 floats = 53.0 MB

    hipLaunchKernelGGL(pack_kernel,      dim3(128),        dim3(256), 0, stream, xyz, xyzw);
    hipLaunchKernelGGL(prep_kernel,      dim3(128),        dim3(128), 0, stream, Wq, bq, Wk, bk, M, u, v, w);
    hipLaunchKernelGGL(knn_kernel,       dim3(8192),       dim3(256), 0, stream, xyzw, idx);
    hipLaunchKernelGGL(tmat_kernel,      dim3(512),        dim3(256), 0, stream, concat, M, v, t);
    hipLaunchKernelGGL(transpose_kernel, dim3(128, 8, 8),  dim3(256), 0, stream, feat, featT);
    hipLaunchKernelGGL(fused_kernel,     dim3(2048),       dim3(256), 0, stream, concat, t, featT, idx, u, w, out);
}